// Round 3
// baseline (1104.358 us; speedup 1.0000x reference)
//
#include <hip/hip_runtime.h>
#include <hip/hip_bf16.h>
#include <cstddef>

// z_e_x: [8,4096,512] fp32 -> BN=32768 rows; codebook: [8192,512] fp32.
// Outputs: codes [BN,512] fp32, zqx_tilde [BN,512] fp32, idx [BN] as fp32.
//
// Numerics (bit-exact-verified): ref dist = fl(x_sq + 2*fl(dot)), cb_sq
// vanishes under fp32 rounding; fl(dot) = sequential fp32 fma chain
// k=0..511 ascending; argmin = first index.
//
// bf16 MFMA computes approx dots (identical ascending-k 16x16x32 chain as
// previous rounds -> bit-identical approx values). GEMM epilogue stores
// per-(row, 128-code block) min + 64-bit pair-mask within blockmin+MARGIN.
// Select expands candidates, rechecks with EXACT fp32 chain -> exact argmin.
//
// THIS ROUND: persistent-block 8-phase GEMM. Round-2 measurement: 2280
// cyc/phase vs 620 cyc matrix work (MfmaUtil 22%) because K=512 gives only
// 4 pipeline iterations/block and 16 serialized generations/CU pay cold
// prologue+drain+epilogue each. Now grid=256 (1 block/CU), each block walks
// 16 M-tiles at fixed N-panel; identical per-iteration vmcnt/barrier ledger,
// pipeline continuous over 64 K-tiles (m201 depth). Epilogue in dedicated
// 12KB LDS with lgkm-only barriers (no vmcnt(0) drain mid-stream).
constexpr int BN   = 32768;
constexpr int DDIM = 512;
constexpr int KC   = 8192;
#define MARGIN 3.0e-4f

typedef __attribute__((ext_vector_type(8))) short short8;    // 8 bf16
typedef __attribute__((ext_vector_type(4))) float f32x4;

__device__ inline unsigned short bf16_rne(float f) {
  unsigned u = __builtin_bit_cast(unsigned, f);
  unsigned r = u + 0x7FFFu + ((u >> 16) & 1u);
  return (unsigned short)(r >> 16);
}

#define GLL16(gp, lp)                                                         \
  __builtin_amdgcn_global_load_lds(                                           \
      (const __attribute__((address_space(1))) unsigned int*)(gp),            \
      (__attribute__((address_space(3))) unsigned int*)(lp), 16, 0, 0)

// ---------------- fused: X fp32 -> bf16 + per-row squared norm -------------
// Summation order identical to the verified vq_xsq (t=0 then t=1, x,y,z,w)
// -> bit-identical xsq. One pass over X instead of two.
__global__ __launch_bounds__(256) void vq_xcvt(const float* __restrict__ X,
                                               unsigned short* __restrict__ Xb,
                                               float* __restrict__ xsq) {
  const int wave = threadIdx.x >> 6;
  const int lane = threadIdx.x & 63;
  const int row = blockIdx.x * 4 + wave;
  const float4* r = (const float4*)(X + (size_t)row * DDIM);
  ushort4* ob = (ushort4*)(Xb + (size_t)row * DDIM);
  float s = 0.f;
#pragma unroll
  for (int t = 0; t < 2; ++t) {
    float4 v = r[lane + 64 * t];
    s += v.x * v.x + v.y * v.y + v.z * v.z + v.w * v.w;
    ushort4 o;
    o.x = bf16_rne(v.x); o.y = bf16_rne(v.y);
    o.z = bf16_rne(v.z); o.w = bf16_rne(v.w);
    ob[lane + 64 * t] = o;
  }
#pragma unroll
  for (int m = 32; m > 0; m >>= 1) s += __shfl_xor(s, m, 64);
  if (lane == 0) xsq[row] = s;
}

// ---------------- per-row squared norms (fallback path only) ----------------
__global__ __launch_bounds__(256) void vq_xsq(const float* __restrict__ X,
                                              float* __restrict__ xsq) {
  const int wave = threadIdx.x >> 6;
  const int lane = threadIdx.x & 63;
  const int row = blockIdx.x * 4 + wave;
  const float4* r = (const float4*)(X + (size_t)row * DDIM);
  float s = 0.f;
#pragma unroll
  for (int t = 0; t < 2; ++t) {
    float4 v = r[lane + 64 * t];
    s += v.x * v.x + v.y * v.y + v.z * v.z + v.w * v.w;
  }
#pragma unroll
  for (int m = 32; m > 0; m >>= 1) s += __shfl_xor(s, m, 64);
  if (lane == 0) xsq[row] = s;
}

// ---------------- fp32 -> bf16 convert (RNE), used for CB ----------------
__global__ __launch_bounds__(256) void vq_cvt(const float* __restrict__ src,
                                              unsigned short* __restrict__ dst,
                                              int n4) {
  int i = blockIdx.x * 256 + threadIdx.x;
  const int stride = gridDim.x * 256;
  for (; i < n4; i += stride) {
    float4 v = ((const float4*)src)[i];
    ushort4 o;
    o.x = bf16_rne(v.x); o.y = bf16_rne(v.y);
    o.z = bf16_rne(v.z); o.w = bf16_rne(v.w);
    ((ushort4*)dst)[i] = o;
  }
}

// -------- persistent bf16 MFMA GEMM, 256^2 tile, 8-phase schedule ---------
// grid = 256 blocks (1/CU), 512 thr = 8 waves (wm = w>>2, wn = w&3).
// Block decode (XCD c = bid&7 serves N-panels 4c..4c+3, L2-resident 1MB):
//   c = bid&7; m = bid>>3; ycol = c*4 + (m>>3); xrun = m&7.
//   col0 = ycol*256 (fixed); tiles t=0..15 at row0 = (xrun*16+t)*256.
// LDS: A[buf][half][128r][8 slots*16B] @0 (buf str 32768), B @65536;
//      epilogue rmh @131072 (8KB), msk @139264 (4KB). Total 143360.
// Swizzle: row r chunk c stored at slot c^(r&7); GLL source pre-inverse-
// swizzled (lane l: chunk (l&7)^((l>>3)&7) of row w*8+(l>>3)).
// K-tile sequence s=0..127 (tile t = s>>3, k = s&7); buf = s&1.
// Per inner iteration ii (consumes s=8t+2ii buf0 in P1-P4, s+1 buf1 P5-P8):
//  stage: P1 buf1.Ah1(s+1) P2 buf1.Bh0(s+1) P3 buf0.Ah0(s+2) P4 buf0.Bh1(s+2)
//         P5 buf0.Ah1(s+2) P6 buf0.Bh0(s+2) P7 buf1.Ah0(s+3) P8 buf1.Bh1(s+3)
//  waits: vmcnt(4) at P4/P8 (2 half-tiles in flight); final iter: P4 vmcnt(0).
// At ii=3 the s+2/s+3 stages target tile t+1 (pAt+262144); suppressed at t=15.
// Ledger verified: entering each P1 outstanding=4 (prev P7/P8); P4's vmcnt(4)
// drains prevP7,prevP8,P1,P2 = the 4 halves of the buf1 tile read in P5-P8;
// P8's vmcnt(4) drains P3-P6 = the 4 halves of the buf0 tile read next P1-P4.
// Epilogue global stores enter the vmcnt queue ahead of younger loads and are
// drained harmlessly by the next counted wait.
__global__ __launch_bounds__(512, 2) void vq_gemm8(const unsigned short* __restrict__ Xb,
                                                   const unsigned short* __restrict__ CBb,
                                                   float* __restrict__ BM,
                                                   unsigned int* __restrict__ Msk) {
  __shared__ __align__(16) unsigned char smem[143360];

  const int tid  = threadIdx.x;
  const int lane = tid & 63;
  const int w    = tid >> 6;
  const int wm   = w >> 2, wn = w & 3;
  const int quad = lane >> 4, c16 = lane & 15;

  const int bid  = blockIdx.x;
  const int xcd  = bid & 7, mm_ = bid >> 3;
  const int ycol = xcd * 4 + (mm_ >> 3);
  const int xrun = mm_ & 7;
  const int col0 = ycol * 256;
  const int row0_base = xrun * 4096;   // rows

  // staging source bases (site0 rows w*8+(l>>3); site1 = +64 rows = +65536B)
  const int srow = w * 8 + (lane >> 3);
  const int qch  = (lane & 7) ^ ((lane >> 3) & 7);
  const unsigned char* pAt = (const unsigned char*)Xb  + (size_t)(row0_base + srow) * 1024 + qch * 16;
  const unsigned char* pB  = (const unsigned char*)CBb + (size_t)(col0 + srow) * 1024 + qch * 16;

  // ds_read per-lane constants
  const int arow = wm * 64 + c16;
  const int brow = wn * 32 + c16;
  const int sx0  = ((0 + quad) ^ (c16 & 7)) * 16;   // kk=0 chunk slot
  const int sx1  = ((4 + quad) ^ (c16 & 7)) * 16;   // kk=1 chunk slot

  f32x4 acc[8][4];
#pragma unroll
  for (int i = 0; i < 8; ++i)
#pragma unroll
    for (int j = 0; j < 4; ++j) acc[i][j] = (f32x4)0.f;

  short8 a[4][2], b[2][2];

#define STG_A(BUF, H, PTR, K)                                                          \
  do {                                                                                 \
    GLL16((PTR) + (size_t)(H) * 131072 + (K) * 128,                                    \
          smem + (BUF) * 32768 + (H) * 16384 + w * 1024);                              \
    GLL16((PTR) + (size_t)(H) * 131072 + 65536 + (K) * 128,                            \
          smem + (BUF) * 32768 + (H) * 16384 + 8192 + w * 1024);                       \
  } while (0)
#define STG_B(BUF, H, K)                                                               \
  do {                                                                                 \
    GLL16(pB + (size_t)(H) * 131072 + (K) * 128,                                       \
          smem + 65536 + (BUF) * 32768 + (H) * 16384 + w * 1024);                      \
    GLL16(pB + (size_t)(H) * 131072 + 65536 + (K) * 128,                               \
          smem + 65536 + (BUF) * 32768 + (H) * 16384 + 8192 + w * 1024);               \
  } while (0)

#define LDA(BUF, H)                                                                    \
  do {                                                                                 \
    _Pragma("unroll") for (int m4_ = 0; m4_ < 4; ++m4_) {                              \
      a[m4_][0] = *(const short8*)(smem + (BUF) * 32768 + (H) * 16384 +                \
                                   (arow + m4_ * 16) * 128 + sx0);                     \
      a[m4_][1] = *(const short8*)(smem + (BUF) * 32768 + (H) * 16384 +                \
                                   (arow + m4_ * 16) * 128 + sx1);                     \
    }                                                                                  \
  } while (0)
#define LDB(BUF, H)                                                                    \
  do {                                                                                 \
    _Pragma("unroll") for (int n1_ = 0; n1_ < 2; ++n1_) {                              \
      b[n1_][0] = *(const short8*)(smem + 65536 + (BUF) * 32768 + (H) * 16384 +        \
                                   (brow + n1_ * 16) * 128 + sx0);                     \
      b[n1_][1] = *(const short8*)(smem + 65536 + (BUF) * 32768 + (H) * 16384 +        \
                                   (brow + n1_ * 16) * 128 + sx1);                     \
    }                                                                                  \
  } while (0)

#define MM(HA, HB)                                                                     \
  do {                                                                                 \
    __builtin_amdgcn_s_setprio(1);                                                     \
    _Pragma("unroll") for (int m4_ = 0; m4_ < 4; ++m4_)                                \
      _Pragma("unroll") for (int n1_ = 0; n1_ < 2; ++n1_) {                            \
        acc[(HA) * 4 + m4_][(HB) * 2 + n1_] = __builtin_amdgcn_mfma_f32_16x16x32_bf16( \
            a[m4_][0], b[n1_][0], acc[(HA) * 4 + m4_][(HB) * 2 + n1_], 0, 0, 0);       \
        acc[(HA) * 4 + m4_][(HB) * 2 + n1_] = __builtin_amdgcn_mfma_f32_16x16x32_bf16( \
            a[m4_][1], b[n1_][1], acc[(HA) * 4 + m4_][(HB) * 2 + n1_], 0, 0, 0);       \
      }                                                                                \
    __builtin_amdgcn_s_setprio(0);                                                     \
  } while (0)

#define BARX   __builtin_amdgcn_s_barrier()
#define SB0    __builtin_amdgcn_sched_barrier(0)
#define WAITK  do { asm volatile("s_waitcnt lgkmcnt(0)" ::: "memory"); SB0; } while (0)
#define VMC4   asm volatile("s_waitcnt vmcnt(4)" ::: "memory")
#define VMC0   asm volatile("s_waitcnt vmcnt(0)" ::: "memory")
#define EBAR   do { asm volatile("s_waitcnt lgkmcnt(0)" ::: "memory"); __builtin_amdgcn_s_barrier(); } while (0)

  float    (*rmh)[2][4] = (float    (*)[2][4])(smem + 131072);  // [256][blk][wn]
  unsigned (*msk)[2][2] = (unsigned (*)[2][2])(smem + 139264);  // [256][blk][word]

  // -------- prologue: s=0 all 4 halves + s=1 {Ah0, Bh1} --------
  STG_A(0, 0, pAt, 0); STG_A(0, 1, pAt, 0);
  STG_B(0, 0, 0);      STG_B(0, 1, 0);
  STG_A(1, 0, pAt, 1);
  STG_B(1, 1, 1);
  VMC4;          // s=0 resident (s=1 halves = newest 4 loads outstanding)
  BARX;

#pragma unroll 1
  for (int t = 0; t < 16; ++t) {
    const bool nl = (t != 15);
    const unsigned char* pAn = pAt + 262144;   // next tile's A base

    // ---- ii = 0 (k = 0,1; stage k=1 finish, k=2 full, k=3 start) ----
    LDA(0, 0); LDB(0, 0); STG_A(1, 1, pAt, 1);        BARX; WAITK; MM(0, 0); SB0; BARX;
    LDB(0, 1);            STG_B(1, 0, 1);             BARX; WAITK; MM(0, 1); SB0; BARX;
    LDA(0, 1);            STG_A(0, 0, pAt, 2);        BARX; WAITK; MM(1, 1); SB0; BARX;
    LDB(0, 0);            STG_B(0, 1, 2); VMC4;       BARX; WAITK; MM(1, 0); SB0; BARX;
    LDA(1, 0); LDB(1, 0); STG_A(0, 1, pAt, 2);        BARX; WAITK; MM(0, 0); SB0; BARX;
    LDB(1, 1);            STG_B(0, 0, 2);             BARX; WAITK; MM(0, 1); SB0; BARX;
    LDA(1, 1);            STG_A(1, 0, pAt, 3);        BARX; WAITK; MM(1, 1); SB0; BARX;
    LDB(1, 0);            STG_B(1, 1, 3); VMC4;       BARX; WAITK; MM(1, 0); SB0; BARX;

    // ---- ii = 1 (k = 2,3) ----
    LDA(0, 0); LDB(0, 0); STG_A(1, 1, pAt, 3);        BARX; WAITK; MM(0, 0); SB0; BARX;
    LDB(0, 1);            STG_B(1, 0, 3);             BARX; WAITK; MM(0, 1); SB0; BARX;
    LDA(0, 1);            STG_A(0, 0, pAt, 4);        BARX; WAITK; MM(1, 1); SB0; BARX;
    LDB(0, 0);            STG_B(0, 1, 4); VMC4;       BARX; WAITK; MM(1, 0); SB0; BARX;
    LDA(1, 0); LDB(1, 0); STG_A(0, 1, pAt, 4);        BARX; WAITK; MM(0, 0); SB0; BARX;
    LDB(1, 1);            STG_B(0, 0, 4);             BARX; WAITK; MM(0, 1); SB0; BARX;
    LDA(1, 1);            STG_A(1, 0, pAt, 5);        BARX; WAITK; MM(1, 1); SB0; BARX;
    LDB(1, 0);            STG_B(1, 1, 5); VMC4;       BARX; WAITK; MM(1, 0); SB0; BARX;

    // ---- ii = 2 (k = 4,5) ----
    LDA(0, 0); LDB(0, 0); STG_A(1, 1, pAt, 5);        BARX; WAITK; MM(0, 0); SB0; BARX;
    LDB(0, 1);            STG_B(1, 0, 5);             BARX; WAITK; MM(0, 1); SB0; BARX;
    LDA(0, 1);            STG_A(0, 0, pAt, 6);        BARX; WAITK; MM(1, 1); SB0; BARX;
    LDB(0, 0);            STG_B(0, 1, 6); VMC4;       BARX; WAITK; MM(1, 0); SB0; BARX;
    LDA(1, 0); LDB(1, 0); STG_A(0, 1, pAt, 6);        BARX; WAITK; MM(0, 0); SB0; BARX;
    LDB(1, 1);            STG_B(0, 0, 6);             BARX; WAITK; MM(0, 1); SB0; BARX;
    LDA(1, 1);            STG_A(1, 0, pAt, 7);        BARX; WAITK; MM(1, 1); SB0; BARX;
    LDB(1, 0);            STG_B(1, 1, 7); VMC4;       BARX; WAITK; MM(1, 0); SB0; BARX;

    // ---- ii = 3 (k = 6,7; stage next tile k=0,1; suppressed at t=15) ----
    LDA(0, 0); LDB(0, 0); STG_A(1, 1, pAt, 7);        BARX; WAITK; MM(0, 0); SB0; BARX;
    LDB(0, 1);            STG_B(1, 0, 7);             BARX; WAITK; MM(0, 1); SB0; BARX;
    LDA(0, 1);            if (nl) STG_A(0, 0, pAn, 0);
                                                      BARX; WAITK; MM(1, 1); SB0; BARX;
    LDB(0, 0);            if (nl) { STG_B(0, 1, 0); VMC4; } else { VMC0; }
                                                      BARX; WAITK; MM(1, 0); SB0; BARX;
    LDA(1, 0); LDB(1, 0); if (nl) STG_A(0, 1, pAn, 0);
                                                      BARX; WAITK; MM(0, 0); SB0; BARX;
    LDB(1, 1);            if (nl) STG_B(0, 0, 0);     BARX; WAITK; MM(0, 1); SB0; BARX;
    LDA(1, 1);            if (nl) STG_A(1, 0, pAn, 1);
                                                      BARX; WAITK; MM(1, 1); SB0; BARX;
    LDB(1, 0);            if (nl) { STG_B(1, 1, 1); VMC4; }
                                                      BARX; WAITK; MM(1, 0); SB0; BARX;

    // ---- tile epilogue (dedicated LDS; lgkm-only barriers so in-flight ----
    // ---- next-tile stages are NOT drained) ----
    const int row0 = row0_base + t * 256;
    ((unsigned*)(smem + 139264))[tid]       = 0u;
    ((unsigned*)(smem + 139264))[tid + 512] = 0u;
#pragma unroll
    for (int m = 0; m < 8; ++m) {
      const int r = (m >> 2) * 128 + wm * 64 + (m & 3) * 16 + quad * 4;
#pragma unroll
      for (int reg = 0; reg < 4; ++reg) {
#pragma unroll
        for (int blk = 0; blk < 2; ++blk) {
          float v = fminf(acc[m][blk * 2 + 0][reg], acc[m][blk * 2 + 1][reg]);
#pragma unroll
          for (int s = 1; s < 16; s <<= 1) v = fminf(v, __shfl_xor(v, s, 64));
          if (c16 == 0) rmh[r + reg][blk][wn] = v;
        }
      }
    }
    EBAR;
#pragma unroll
    for (int m = 0; m < 8; ++m) {
      const int r = (m >> 2) * 128 + wm * 64 + (m & 3) * 16 + quad * 4;
#pragma unroll
      for (int reg = 0; reg < 4; ++reg) {
#pragma unroll
        for (int blk = 0; blk < 2; ++blk) {
          float thr = fminf(fminf(rmh[r + reg][blk][0], rmh[r + reg][blk][1]),
                            fminf(rmh[r + reg][blk][2], rmh[r + reg][blk][3])) + MARGIN;
#pragma unroll
          for (int n1 = 0; n1 < 2; ++n1) {
            if (acc[m][blk * 2 + n1][reg] <= thr) {
              int pb = wn * 16 + n1 * 8 + (c16 >> 1);   // pair 0..63 in block
              atomicOr(&msk[r + reg][blk][pb >> 5], 1u << (pb & 31));
            }
          }
        }
      }
    }
    EBAR;
    {
      const int r = tid >> 1, blk = tid & 1;
      float bm = fminf(fminf(rmh[r][blk][0], rmh[r][blk][1]),
                       fminf(rmh[r][blk][2], rmh[r][blk][3]));
      size_t o = (size_t)(row0 + r) * 64 + (size_t)ycol * 2 + blk;
      BM[o]          = bm;
      Msk[o * 2 + 0] = msk[r][blk][0];
      Msk[o * 2 + 1] = msk[r][blk][1];
    }
#pragma unroll
    for (int i = 0; i < 8; ++i)
#pragma unroll
      for (int j = 0; j < 4; ++j) acc[i][j] = (f32x4)0.f;

    pAt = pAn;
  }
}

// -------- candidate expansion + exact fp32 recheck + fused gather ---------
__global__ __launch_bounds__(256) void vq_select(const float* __restrict__ X,
                                                 const float* __restrict__ CB,
                                                 const float* __restrict__ xsq,
                                                 const float* __restrict__ BM,
                                                 const unsigned int* __restrict__ Msk,
                                                 float* __restrict__ idx_f,
                                                 float* __restrict__ out_codes,
                                                 float* __restrict__ out_zqx) {
  __shared__ unsigned short cand[4][128];
  __shared__ int cnt[4];
  const int lane = threadIdx.x & 63;
  const int w    = threadIdx.x >> 6;
  const int row  = blockIdx.x * 4 + w;

  if (lane == 0) cnt[w] = 0;
  __syncthreads();

  const size_t bo = (size_t)row * 64 + lane;
  float bmv = BM[bo];
  float g = bmv;
#pragma unroll
  for (int m = 1; m < 64; m <<= 1) g = fminf(g, __shfl_xor(g, m, 64));
  if (bmv <= g + MARGIN) {
    unsigned m0 = Msk[bo * 2 + 0], m1 = Msk[bo * 2 + 1];
    while (m0) {
      int p = __ffs(m0) - 1; m0 &= m0 - 1;
      int base = lane * 128 + p * 2;
      int o = atomicAdd(&cnt[w], 2);
      if (o + 1 < 128) { cand[w][o] = (unsigned short)base; cand[w][o + 1] = (unsigned short)(base + 1); }
    }
    while (m1) {
      int p = __ffs(m1) - 1; m1 &= m1 - 1;
      int base = lane * 128 + 64 + p * 2;
      int o = atomicAdd(&cnt[w], 2);
      if (o + 1 < 128) { cand[w][o] = (unsigned short)base; cand[w][o + 1] = (unsigned short)(base + 1); }
    }
  }
  __syncthreads();

  int n = cnt[w]; n = n > 128 ? 128 : n;
  float bd = __builtin_inff();
  int   bi = 0x7fffffff;
  const float4* xr = (const float4*)(X + (size_t)row * DDIM);
  const float   xs = xsq[row];
  for (int c = lane; c < n; c += 64) {
    int code = cand[w][c];
    const float4* cr = (const float4*)(CB + (size_t)code * DDIM);
    float acc = 0.f;   // EXACT chain: k ascending, single fp32 fma accumulator
#pragma unroll 4
    for (int k = 0; k < 128; ++k) {
      float4 xv = xr[k], cv = cr[k];
      acc = fmaf(xv.x, cv.x, acc);
      acc = fmaf(xv.y, cv.y, acc);
      acc = fmaf(xv.z, cv.z, acc);
      acc = fmaf(xv.w, cv.w, acc);
    }
    float d = fmaf(2.f, acc, xs);
    if (d < bd || (d == bd && code < bi)) { bd = d; bi = code; }
  }
#pragma unroll
  for (int m = 1; m < 64; m <<= 1) {
    float od = __shfl_xor(bd, m, 64);
    int   oi = __shfl_xor(bi, m, 64);
    if (od < bd || (od == bd && oi < bi)) { bd = od; bi = oi; }
  }
  if (lane == 0) idx_f[row] = (float)bi;
  // fused gather: bi is uniform across the wave after the butterfly
  const float4* cr2 = (const float4*)(CB + (size_t)bi * DDIM);
  float4* oc = (float4*)(out_codes + (size_t)row * DDIM);
  float4* oz = (float4*)(out_zqx   + (size_t)row * DDIM);
#pragma unroll
  for (int t = 0; t < 2; ++t) {
    float4 v = cr2[lane + 64 * t];
    oc[lane + 64 * t] = v;
    oz[lane + 64 * t] = v;
  }
}

// ---------------- gather (fallback path only) ----------------
__global__ __launch_bounds__(256) void vq_gather(const float* __restrict__ CB,
                                                 const int* __restrict__ idx_i,
                                                 float* __restrict__ out_codes,
                                                 float* __restrict__ out_zqx) {
  const int t = threadIdx.x;
  const int r = blockIdx.x * 2 + (t >> 7);
  const int q = t & 127;
  const int k = idx_i[r];
  float4 v = *(const float4*)(CB + (size_t)k * DDIM + q * 4);
  *(float4*)(out_codes + (size_t)r * DDIM + q * 4) = v;
  *(float4*)(out_zqx   + (size_t)r * DDIM + q * 4) = v;
}

// ---------------- fallback: fp32 fused GEMM+argmin (known-good) ----
constexpr int FMT = 64, FNT = 128, FDC = 32;
constexpr int FAS = FMT + 2, FBS = FNT + 2;
__global__ __launch_bounds__(256, 2) void vq_argmin_fb(const float* __restrict__ X,
                                                       const float* __restrict__ CB,
                                                       const float* __restrict__ xsq,
                                                       int* __restrict__ idx_i,
                                                       float* __restrict__ idx_f) {
  __shared__ float As[FDC][FAS];
  __shared__ float Bs[FDC][FBS];
  const int tid = threadIdx.x;
  const int tx = tid & 15, ty = tid >> 4;
  const int row_base = blockIdx.x * FMT;
  float xs[4];
#pragma unroll
  for (int i = 0; i < 4; ++i) xs[i] = xsq[row_base + ty * 4 + i];
  float bestv[4]; int besti[4];
#pragma unroll
  for (int i = 0; i < 4; ++i) { bestv[i] = __builtin_inff(); besti[i] = 0; }
  for (int c0 = 0; c0 < KC; c0 += FNT) {
    float acc[4][8];
#pragma unroll
    for (int i = 0; i < 4; ++i)
#pragma unroll
      for (int j = 0; j < 8; ++j) acc[i][j] = 0.f;
    for (int d0 = 0; d0 < DDIM; d0 += FDC) {
      __syncthreads();
#pragma unroll
      for (int s = 0; s < 2; ++s) {
        int f = tid + 256 * s; int r = f >> 3, q = f & 7;
        float4 v = *(const float4*)(X + (size_t)(row_base + r) * DDIM + d0 + q * 4);
        As[q * 4 + 0][r] = v.x; As[q * 4 + 1][r] = v.y;
        As[q * 4 + 2][r] = v.z; As[q * 4 + 3][r] = v.w;
      }
#pragma unroll
      for (int s = 0; s < 4; ++s) {
        int f = tid + 256 * s; int r = f >> 3, q = f & 7;
        float4 v = *(const float4*)(CB + (size_t)(c0 + r) * DDIM + d0 + q * 4);
        Bs[q * 4 + 0][r] = v.x; Bs[q * 4 + 1][r] = v.y;
        Bs[q * 4 + 2][r] = v.z; Bs[q * 4 + 3][r] = v.w;
      }
      __syncthreads();
#pragma unroll
      for (int kk = 0; kk < FDC; ++kk) {
        float a[4], b[8];
        *(float2*)&a[0] = *(const float2*)&As[kk][ty * 4 + 0];
        *(float2*)&a[2] = *(const float2*)&As[kk][ty * 4 + 2];
        *(float2*)&b[0] = *(const float2*)&Bs[kk][tx * 4 + 0];
        *(float2*)&b[2] = *(const float2*)&Bs[kk][tx * 4 + 2];
        *(float2*)&b[4] = *(const float2*)&Bs[kk][64 + tx * 4 + 0];
        *(float2*)&b[6] = *(const float2*)&Bs[kk][64 + tx * 4 + 2];
#pragma unroll
        for (int i = 0; i < 4; ++i)
#pragma unroll
          for (int j = 0; j < 8; ++j) acc[i][j] = fmaf(a[i], b[j], acc[i][j]);
      }
    }
#pragma unroll
    for (int j = 0; j < 8; ++j) {
      int c = c0 + ((j < 4) ? (tx * 4 + j) : (64 + tx * 4 + (j - 4)));
#pragma unroll
      for (int i = 0; i < 4; ++i) {
        float d = fmaf(2.f, acc[i][j], xs[i]);
        if (d < bestv[i] || (d == bestv[i] && c < besti[i])) { bestv[i] = d; besti[i] = c; }
      }
    }
  }
#pragma unroll
  for (int m = 1; m < 16; m <<= 1) {
#pragma unroll
    for (int i = 0; i < 4; ++i) {
      float ov = __shfl_xor(bestv[i], m, 64);
      int   oi = __shfl_xor(besti[i], m, 64);
      if (ov < bestv[i] || (ov == bestv[i] && oi < besti[i])) { bestv[i] = ov; besti[i] = oi; }
    }
  }
  if (tx == 0) {
#pragma unroll
    for (int i = 0; i < 4; ++i) {
      int r = row_base + ty * 4 + i;
      idx_i[r] = besti[i];
      idx_f[r] = (float)besti[i];
    }
  }
}

extern "C" void kernel_launch(void* const* d_in, const int* in_sizes, int n_in,
                              void* d_out, int out_size, void* d_ws, size_t ws_size,
                              hipStream_t stream) {
  const float* X  = (const float*)d_in[0];
  const float* CB = (const float*)d_in[1];

  float* out       = (float*)d_out;
  float* out_codes = out;
  float* out_zqx   = out + (size_t)BN * DDIM;
  float* out_idxf  = out + 2 * (size_t)BN * DDIM;

  unsigned char* w0 = (unsigned char*)d_ws;
  const size_t NEED = (64ull << 20) + 2 * (size_t)BN * 4;

  if (ws_size >= NEED) {
    unsigned short* Xb  = (unsigned short*)w0;                    // 32 MB
    unsigned short* CBb = (unsigned short*)(w0 + (32ull << 20));  //  8 MB
    float*        BM    = (float*)(w0 + (40ull << 20));           //  8 MB
    unsigned int* Msk   = (unsigned int*)(w0 + (48ull << 20));    // 16 MB
    float*        xsq   = (float*)(w0 + (64ull << 20));

    vq_xcvt  <<<BN / 4, 256, 0, stream>>>(X, Xb, xsq);
    vq_cvt   <<<128, 256, 0, stream>>>(CB, CBb, KC * (DDIM / 4));
    vq_gemm8 <<<256, 512, 0, stream>>>(Xb, CBb, BM, Msk);
    vq_select<<<BN / 4, 256, 0, stream>>>(X, CB, xsq, BM, Msk, out_idxf,
                                          out_codes, out_zqx);
  } else {
    float* xsq   = (float*)w0;
    int*   idx_i = (int*)(w0 + (size_t)BN * 4);
    vq_xsq      <<<BN / 4, 256, 0, stream>>>(X, xsq);
    vq_argmin_fb<<<BN / FMT, 256, 0, stream>>>(X, CB, xsq, idx_i, out_idxf);
    vq_gather   <<<BN / 2, 256, 0, stream>>>(CB, idx_i, out_codes, out_zqx);
  }
}

// Round 4
// 734.125 us; speedup vs baseline: 1.5043x; 1.5043x over previous
//
#include <hip/hip_runtime.h>
#include <hip/hip_bf16.h>
#include <cstddef>

// z_e_x: [8,4096,512] fp32 -> BN=32768 rows; codebook: [8192,512] fp32.
// Outputs: codes [BN,512] fp32, zqx_tilde [BN,512] fp32, idx [BN] as fp32.
//
// Numerics (bit-exact-verified): ref dist = fl(x_sq + 2*fl(dot)), cb_sq
// vanishes under fp32 rounding; fl(dot) = sequential fp32 fma chain
// k=0..511 ascending; argmin = first index.
//
// bf16 MFMA computes approx dots; GEMM epilogue stores per-(row,128-code
// block) min + 64-bit pair-mask within blockmin+MARGIN; select expands
// candidates and rechecks with the EXACT fp32 chain -> bit-exact argmin.
//
// ROUND-4 postmortem notes:
//  - 8-phase 256^2 GEMM (rounds 2-3) parked: 2500-3200 cyc/phase vs m201's
//    824; warm-L3 replays (93MB fetch) ran at identical duration -> skeleton/
//    latency-bound, not BW. Reverted to round-0 128^2 GEMM (448 us verified).
//  - Tail (~420 us) invariant across rounds despite fusions -> vq_select
//    recheck core: per-lane serial X/CB walks at unroll-4 (~4-deep MLP),
//    HBM-cold X -> ~29k cyc/row. Fixed: stage X row in LDS cooperatively,
//    CB walk unroll 8; identical values & order -> bit-exact.
constexpr int BN   = 32768;
constexpr int DDIM = 512;
constexpr int KC   = 8192;
#define MARGIN 3.0e-4f

typedef __attribute__((ext_vector_type(8))) short short8;    // 8 bf16
typedef __attribute__((ext_vector_type(4))) float f32x4;

__device__ inline int fsw(int m) { return (m + (m >> 2)) & 3; }

__device__ inline unsigned short bf16_rne(float f) {
  unsigned u = __builtin_bit_cast(unsigned, f);
  unsigned r = u + 0x7FFFu + ((u >> 16) & 1u);
  return (unsigned short)(r >> 16);
}

#define GLL16(gp, lp)                                                         \
  __builtin_amdgcn_global_load_lds(                                           \
      (const __attribute__((address_space(1))) unsigned int*)(gp),            \
      (__attribute__((address_space(3))) unsigned int*)(lp), 16, 0, 0)

// ---------------- fused: X fp32 -> bf16 + per-row squared norm -------------
// Summation order identical to the verified vq_xsq (t=0 then t=1, x,y,z,w)
// -> bit-identical xsq. One pass over X instead of two.
__global__ __launch_bounds__(256) void vq_xcvt(const float* __restrict__ X,
                                               unsigned short* __restrict__ Xb,
                                               float* __restrict__ xsq) {
  const int wave = threadIdx.x >> 6;
  const int lane = threadIdx.x & 63;
  const int row = blockIdx.x * 4 + wave;
  const float4* r = (const float4*)(X + (size_t)row * DDIM);
  ushort4* ob = (ushort4*)(Xb + (size_t)row * DDIM);
  float s = 0.f;
#pragma unroll
  for (int t = 0; t < 2; ++t) {
    float4 v = r[lane + 64 * t];
    s += v.x * v.x + v.y * v.y + v.z * v.z + v.w * v.w;
    ushort4 o;
    o.x = bf16_rne(v.x); o.y = bf16_rne(v.y);
    o.z = bf16_rne(v.z); o.w = bf16_rne(v.w);
    ob[lane + 64 * t] = o;
  }
#pragma unroll
  for (int m = 32; m > 0; m >>= 1) s += __shfl_xor(s, m, 64);
  if (lane == 0) xsq[row] = s;
}

// ---------------- per-row squared norms (fallback path only) ----------------
__global__ __launch_bounds__(256) void vq_xsq(const float* __restrict__ X,
                                              float* __restrict__ xsq) {
  const int wave = threadIdx.x >> 6;
  const int lane = threadIdx.x & 63;
  const int row = blockIdx.x * 4 + wave;
  const float4* r = (const float4*)(X + (size_t)row * DDIM);
  float s = 0.f;
#pragma unroll
  for (int t = 0; t < 2; ++t) {
    float4 v = r[lane + 64 * t];
    s += v.x * v.x + v.y * v.y + v.z * v.z + v.w * v.w;
  }
#pragma unroll
  for (int m = 32; m > 0; m >>= 1) s += __shfl_xor(s, m, 64);
  if (lane == 0) xsq[row] = s;
}

// ---------------- fp32 -> bf16 convert (RNE), used for CB ----------------
__global__ __launch_bounds__(256) void vq_cvt(const float* __restrict__ src,
                                              unsigned short* __restrict__ dst,
                                              int n4) {
  int i = blockIdx.x * 256 + threadIdx.x;
  const int stride = gridDim.x * 256;
  for (; i < n4; i += stride) {
    float4 v = ((const float4*)src)[i];
    ushort4 o;
    o.x = bf16_rne(v.x); o.y = bf16_rne(v.y);
    o.z = bf16_rne(v.z); o.w = bf16_rne(v.w);
    ((ushort4*)dst)[i] = o;
  }
}

// ---------------- bf16 MFMA GEMM + blockmin/mask epilogue (round-0) --------
// 128x128 tile, 256 thr = 4 waves (wave tile 64x64 = 4x4 frags of 16x16x32).
// LDS rows: 32 bf16 = 4 quarters of 16B; physical quarter = q ^ fsw(m).
// global_load_lds: wave-uniform LDS base + lane*16; lane loads the global
// quarter that belongs in its slot (same fsw formula as fragment reads).
__global__ __launch_bounds__(256) void vq_gemm(const unsigned short* __restrict__ Xb,
                                               const unsigned short* __restrict__ CBb,
                                               float* __restrict__ BM,
                                               unsigned int* __restrict__ Msk) {
  __shared__ __align__(16) unsigned char As[8192];
  __shared__ __align__(16) unsigned char Bs[8192];
  __shared__ float rmh[128][2];
  __shared__ unsigned int msk[128][2];

  const int tid  = threadIdx.x;
  const int lane = tid & 63;
  const int w    = tid >> 6;
  const int wm   = w >> 1, wn = w & 1;
  const int row0 = blockIdx.x * 128;
  const int col0 = blockIdx.y * 128;
  const int quad = lane >> 4, c16 = lane & 15;

  // per-lane staging sources for this wave's two granules (16 rows each)
  const int g1 = 2 * w, g2 = 2 * w + 1;
  const int mloc = lane >> 2, qp = lane & 3;
  const int ma1 = g1 * 16 + mloc, ma2 = g2 * 16 + mloc;
  const unsigned char* pA1 = (const unsigned char*)Xb +
      (size_t)(row0 + ma1) * 1024 + (size_t)((qp ^ fsw(ma1)) * 16);
  const unsigned char* pA2 = (const unsigned char*)Xb +
      (size_t)(row0 + ma2) * 1024 + (size_t)((qp ^ fsw(ma2)) * 16);
  const unsigned char* pB1 = (const unsigned char*)CBb +
      (size_t)(col0 + ma1) * 1024 + (size_t)((qp ^ fsw(ma1)) * 16);
  const unsigned char* pB2 = (const unsigned char*)CBb +
      (size_t)(col0 + ma2) * 1024 + (size_t)((qp ^ fsw(ma2)) * 16);

  f32x4 acc[4][4];
#pragma unroll
  for (int i = 0; i < 4; ++i)
#pragma unroll
    for (int j = 0; j < 4; ++j) acc[i][j] = (f32x4)0.f;

  for (int kc = 0; kc < 16; ++kc) {
    const size_t ko = (size_t)kc * 64;
    GLL16(pA1 + ko, As + g1 * 1024);
    GLL16(pA2 + ko, As + g2 * 1024);
    GLL16(pB1 + ko, Bs + g1 * 1024);
    GLL16(pB2 + ko, Bs + g2 * 1024);
    __syncthreads();

    short8 a[4], b[4];
#pragma unroll
    for (int i = 0; i < 4; ++i) {
      int m = wm * 64 + i * 16 + c16;
      a[i] = *(const short8*)(As + m * 64 + ((quad ^ fsw(m)) * 16));
      int n = wn * 64 + i * 16 + c16;
      b[i] = *(const short8*)(Bs + n * 64 + ((quad ^ fsw(n)) * 16));
    }
#pragma unroll
    for (int i = 0; i < 4; ++i)
#pragma unroll
      for (int j = 0; j < 4; ++j)
        acc[i][j] = __builtin_amdgcn_mfma_f32_16x16x32_bf16(a[i], b[j], acc[i][j], 0, 0, 0);
    __syncthreads();
  }

  // ---- epilogue: per-row min over this 128-col block + near-min pair mask.
  // C/D layout: col = lane&15, row = quad*4 + reg (learn_hip m89).
  if (tid < 128) { msk[tid][0] = 0u; msk[tid][1] = 0u; }
  float rmloc[4][4];
#pragma unroll
  for (int i = 0; i < 4; ++i)
#pragma unroll
    for (int reg = 0; reg < 4; ++reg) {
      float v = acc[i][0][reg];
#pragma unroll
      for (int j = 1; j < 4; ++j) v = fminf(v, acc[i][j][reg]);
#pragma unroll
      for (int m = 1; m < 16; m <<= 1) v = fminf(v, __shfl_xor(v, m, 64));
      rmloc[i][reg] = v;
      if (c16 == 0) rmh[wm * 64 + i * 16 + quad * 4 + reg][wn] = v;
    }
  __syncthreads();
#pragma unroll
  for (int i = 0; i < 4; ++i)
#pragma unroll
    for (int reg = 0; reg < 4; ++reg) {
      int r = wm * 64 + i * 16 + quad * 4 + reg;
      float thr = fminf(rmh[r][0], rmh[r][1]) + MARGIN;
#pragma unroll
      for (int j = 0; j < 4; ++j) {
        float v = acc[i][j][reg];
        if (v <= thr) {
          int cl = wn * 64 + j * 16 + c16;   // col in tile, 0..127
          int p = cl >> 1;                    // pair 0..63
          atomicOr(&msk[r][p >> 5], 1u << (p & 31));
        }
      }
    }
  __syncthreads();
  if (tid < 128) {
    size_t o = (size_t)(row0 + tid) * 64 + blockIdx.y;
    BM[o] = fminf(rmh[tid][0], rmh[tid][1]);
    Msk[o * 2 + 0] = msk[tid][0];
    Msk[o * 2 + 1] = msk[tid][1];
  }
}

// -------- candidate expansion + exact fp32 recheck + fused gather ---------
// Recheck data path: X row staged in LDS by the whole wave (coalesced);
// serial exact chain reads X from LDS and CB from global with unroll 8
// (8-deep MLP). Values and accumulation order identical -> bit-exact.
__global__ __launch_bounds__(256) void vq_select(const float* __restrict__ X,
                                                 const float* __restrict__ CB,
                                                 const float* __restrict__ xsq,
                                                 const float* __restrict__ BM,
                                                 const unsigned int* __restrict__ Msk,
                                                 float* __restrict__ idx_f,
                                                 float* __restrict__ out_codes,
                                                 float* __restrict__ out_zqx) {
  __shared__ float xrow[4][DDIM];          // 8 KB: per-wave staged X row
  __shared__ unsigned short cand[4][128];
  __shared__ int cnt[4];
  const int lane = threadIdx.x & 63;
  const int w    = threadIdx.x >> 6;
  const int row  = blockIdx.x * 4 + w;

  if (lane == 0) cnt[w] = 0;

  // cooperative X-row stage (coalesced: 64 lanes x 2 float4)
  const float4* xr = (const float4*)(X + (size_t)row * DDIM);
  float4* xl4 = (float4*)xrow[w];
  xl4[lane]      = xr[lane];
  xl4[lane + 64] = xr[lane + 64];
  __syncthreads();

  const size_t bo = (size_t)row * 64 + lane;
  float bmv = BM[bo];
  float g = bmv;
#pragma unroll
  for (int m = 1; m < 64; m <<= 1) g = fminf(g, __shfl_xor(g, m, 64));
  if (bmv <= g + MARGIN) {
    unsigned m0 = Msk[bo * 2 + 0], m1 = Msk[bo * 2 + 1];
    while (m0) {
      int p = __ffs(m0) - 1; m0 &= m0 - 1;
      int base = lane * 128 + p * 2;
      int o = atomicAdd(&cnt[w], 2);
      if (o + 1 < 128) { cand[w][o] = (unsigned short)base; cand[w][o + 1] = (unsigned short)(base + 1); }
    }
    while (m1) {
      int p = __ffs(m1) - 1; m1 &= m1 - 1;
      int base = lane * 128 + 64 + p * 2;
      int o = atomicAdd(&cnt[w], 2);
      if (o + 1 < 128) { cand[w][o] = (unsigned short)base; cand[w][o + 1] = (unsigned short)(base + 1); }
    }
  }
  __syncthreads();

  int n = cnt[w]; n = n > 128 ? 128 : n;
  float bd = __builtin_inff();
  int   bi = 0x7fffffff;
  const float4* xl = (const float4*)xrow[w];
  const float   xs = xsq[row];
  for (int c = lane; c < n; c += 64) {
    int code = cand[w][c];
    const float4* cr = (const float4*)(CB + (size_t)code * DDIM);
    float acc = 0.f;   // EXACT chain: k ascending, single fp32 fma accumulator
#pragma unroll 8
    for (int k = 0; k < 128; ++k) {
      float4 xv = xl[k], cv = cr[k];
      acc = fmaf(xv.x, cv.x, acc);
      acc = fmaf(xv.y, cv.y, acc);
      acc = fmaf(xv.z, cv.z, acc);
      acc = fmaf(xv.w, cv.w, acc);
    }
    float d = fmaf(2.f, acc, xs);
    if (d < bd || (d == bd && code < bi)) { bd = d; bi = code; }
  }
#pragma unroll
  for (int m = 1; m < 64; m <<= 1) {
    float od = __shfl_xor(bd, m, 64);
    int   oi = __shfl_xor(bi, m, 64);
    if (od < bd || (od == bd && oi < bi)) { bd = od; bi = oi; }
  }
  if (lane == 0) idx_f[row] = (float)bi;
  // fused gather: bi is uniform across the wave after the butterfly
  const float4* cr2 = (const float4*)(CB + (size_t)bi * DDIM);
  float4* oc = (float4*)(out_codes + (size_t)row * DDIM);
  float4* oz = (float4*)(out_zqx   + (size_t)row * DDIM);
#pragma unroll
  for (int t = 0; t < 2; ++t) {
    float4 v = cr2[lane + 64 * t];
    oc[lane + 64 * t] = v;
    oz[lane + 64 * t] = v;
  }
}

// ---------------- gather (fallback path only) ----------------
__global__ __launch_bounds__(256) void vq_gather(const float* __restrict__ CB,
                                                 const int* __restrict__ idx_i,
                                                 float* __restrict__ out_codes,
                                                 float* __restrict__ out_zqx) {
  const int t = threadIdx.x;
  const int r = blockIdx.x * 2 + (t >> 7);
  const int q = t & 127;
  const int k = idx_i[r];
  float4 v = *(const float4*)(CB + (size_t)k * DDIM + q * 4);
  *(float4*)(out_codes + (size_t)r * DDIM + q * 4) = v;
  *(float4*)(out_zqx   + (size_t)r * DDIM + q * 4) = v;
}

// ---------------- fallback: fp32 fused GEMM+argmin (known-good) ----
constexpr int FMT = 64, FNT = 128, FDC = 32;
constexpr int FAS = FMT + 2, FBS = FNT + 2;
__global__ __launch_bounds__(256, 2) void vq_argmin_fb(const float* __restrict__ X,
                                                       const float* __restrict__ CB,
                                                       const float* __restrict__ xsq,
                                                       int* __restrict__ idx_i,
                                                       float* __restrict__ idx_f) {
  __shared__ float As[FDC][FAS];
  __shared__ float Bs[FDC][FBS];
  const int tid = threadIdx.x;
  const int tx = tid & 15, ty = tid >> 4;
  const int row_base = blockIdx.x * FMT;
  float xs[4];
#pragma unroll
  for (int i = 0; i < 4; ++i) xs[i] = xsq[row_base + ty * 4 + i];
  float bestv[4]; int besti[4];
#pragma unroll
  for (int i = 0; i < 4; ++i) { bestv[i] = __builtin_inff(); besti[i] = 0; }
  for (int c0 = 0; c0 < KC; c0 += FNT) {
    float acc[4][8];
#pragma unroll
    for (int i = 0; i < 4; ++i)
#pragma unroll
      for (int j = 0; j < 8; ++j) acc[i][j] = 0.f;
    for (int d0 = 0; d0 < DDIM; d0 += FDC) {
      __syncthreads();
#pragma unroll
      for (int s = 0; s < 2; ++s) {
        int f = tid + 256 * s; int r = f >> 3, q = f & 7;
        float4 v = *(const float4*)(X + (size_t)(row_base + r) * DDIM + d0 + q * 4);
        As[q * 4 + 0][r] = v.x; As[q * 4 + 1][r] = v.y;
        As[q * 4 + 2][r] = v.z; As[q * 4 + 3][r] = v.w;
      }
#pragma unroll
      for (int s = 0; s < 4; ++s) {
        int f = tid + 256 * s; int r = f >> 3, q = f & 7;
        float4 v = *(const float4*)(CB + (size_t)(c0 + r) * DDIM + d0 + q * 4);
        Bs[q * 4 + 0][r] = v.x; Bs[q * 4 + 1][r] = v.y;
        Bs[q * 4 + 2][r] = v.z; Bs[q * 4 + 3][r] = v.w;
      }
      __syncthreads();
#pragma unroll
      for (int kk = 0; kk < FDC; ++kk) {
        float a[4], b[8];
        *(float2*)&a[0] = *(const float2*)&As[kk][ty * 4 + 0];
        *(float2*)&a[2] = *(const float2*)&As[kk][ty * 4 + 2];
        *(float2*)&b[0] = *(const float2*)&Bs[kk][tx * 4 + 0];
        *(float2*)&b[2] = *(const float2*)&Bs[kk][tx * 4 + 2];
        *(float2*)&b[4] = *(const float2*)&Bs[kk][64 + tx * 4 + 0];
        *(float2*)&b[6] = *(const float2*)&Bs[kk][64 + tx * 4 + 2];
#pragma unroll
        for (int i = 0; i < 4; ++i)
#pragma unroll
          for (int j = 0; j < 8; ++j) acc[i][j] = fmaf(a[i], b[j], acc[i][j]);
      }
    }
#pragma unroll
    for (int j = 0; j < 8; ++j) {
      int c = c0 + ((j < 4) ? (tx * 4 + j) : (64 + tx * 4 + (j - 4)));
#pragma unroll
      for (int i = 0; i < 4; ++i) {
        float d = fmaf(2.f, acc[i][j], xs[i]);
        if (d < bestv[i] || (d == bestv[i] && c < besti[i])) { bestv[i] = d; besti[i] = c; }
      }
    }
  }
#pragma unroll
  for (int m = 1; m < 16; m <<= 1) {
#pragma unroll
    for (int i = 0; i < 4; ++i) {
      float ov = __shfl_xor(bestv[i], m, 64);
      int   oi = __shfl_xor(besti[i], m, 64);
      if (ov < bestv[i] || (ov == bestv[i] && oi < besti[i])) { bestv[i] = ov; besti[i] = oi; }
    }
  }
  if (tx == 0) {
#pragma unroll
    for (int i = 0; i < 4; ++i) {
      int r = row_base + ty * 4 + i;
      idx_i[r] = besti[i];
      idx_f[r] = (float)besti[i];
    }
  }
}

extern "C" void kernel_launch(void* const* d_in, const int* in_sizes, int n_in,
                              void* d_out, int out_size, void* d_ws, size_t ws_size,
                              hipStream_t stream) {
  const float* X  = (const float*)d_in[0];
  const float* CB = (const float*)d_in[1];

  float* out       = (float*)d_out;
  float* out_codes = out;
  float* out_zqx   = out + (size_t)BN * DDIM;
  float* out_idxf  = out + 2 * (size_t)BN * DDIM;

  unsigned char* w0 = (unsigned char*)d_ws;
  const size_t NEED = (64ull << 20) + 2 * (size_t)BN * 4;

  if (ws_size >= NEED) {
    unsigned short* Xb  = (unsigned short*)w0;                    // 32 MB
    unsigned short* CBb = (unsigned short*)(w0 + (32ull << 20));  //  8 MB
    float*        BM    = (float*)(w0 + (40ull << 20));           //  8 MB
    unsigned int* Msk   = (unsigned int*)(w0 + (48ull << 20));    // 16 MB
    float*        xsq   = (float*)(w0 + (64ull << 20));

    vq_xcvt  <<<BN / 4, 256, 0, stream>>>(X, Xb, xsq);
    vq_cvt   <<<128, 256, 0, stream>>>(CB, CBb, KC * (DDIM / 4));
    vq_gemm  <<<dim3(BN / 128, KC / 128), 256, 0, stream>>>(Xb, CBb, BM, Msk);
    vq_select<<<BN / 4, 256, 0, stream>>>(X, CB, xsq, BM, Msk, out_idxf,
                                          out_codes, out_zqx);
  } else {
    float* xsq   = (float*)w0;
    int*   idx_i = (int*)(w0 + (size_t)BN * 4);
    vq_xsq      <<<BN / 4, 256, 0, stream>>>(X, xsq);
    vq_argmin_fb<<<BN / FMT, 256, 0, stream>>>(X, CB, xsq, idx_i, out_idxf);
    vq_gather   <<<BN / 2, 256, 0, stream>>>(CB, idx_i, out_codes, out_zqx);
  }
}

// Round 5
// 715.360 us; speedup vs baseline: 1.5438x; 1.0262x over previous
//
#include <hip/hip_runtime.h>
#include <hip/hip_bf16.h>
#include <cstddef>

// z_e_x: [8,4096,512] fp32 -> BN=32768 rows; codebook: [8192,512] fp32.
// Outputs: codes [BN,512] fp32, zqx_tilde [BN,512] fp32, idx [BN] as fp32.
//
// Numerics (bit-exact-verified): ref dist = fl(x_sq + 2*fl(dot)), cb_sq
// vanishes under fp32 rounding; fl(dot) = sequential fp32 fma chain
// k=0..511 ascending; argmin = first index.
//
// bf16 MFMA computes approx dots; GEMM epilogue stores per-(row,128-code
// block) min + 64-bit pair-mask within blockmin+MARGIN; select expands
// candidates and rechecks with the EXACT fp32 chain -> bit-exact argmin.
//
// ROUND-5: round-4 diagnosis = gemm is staging-LATENCY-bound (serial
// stage->sync->compute->sync; warm-L3 replay at same dur proves not BW).
// Fix, on the verified round-0 kernel (NOT the failed 8-phase rewrite):
//  (1) 2-phase prefetch: double-buffered LDS, issue next K-step's
//      global_load_lds BEFORE current compute; closing __syncthreads
//      (vmcnt drain) lands after the compute phase -> latency hidden.
//      One barrier per K-step instead of two.
//  (2) 128x256 tile (wave-tile 64x128, acc[4][8]): 2x MFMA per staged
//      byte/barrier; each wave owns one full 128-col BM block -> epilogue
//      wave-private (no cross-wave combine).
// Per-(row,col) MFMA chain identical (ascending kc, 16 steps) -> dots
// bit-identical -> margin proof / BM+Msk format / select untouched.
constexpr int BN   = 32768;
constexpr int DDIM = 512;
constexpr int KC   = 8192;
#define MARGIN 3.0e-4f

typedef __attribute__((ext_vector_type(8))) short short8;    // 8 bf16
typedef __attribute__((ext_vector_type(4))) float f32x4;

__device__ inline int fsw(int m) { return (m + (m >> 2)) & 3; }

__device__ inline unsigned short bf16_rne(float f) {
  unsigned u = __builtin_bit_cast(unsigned, f);
  unsigned r = u + 0x7FFFu + ((u >> 16) & 1u);
  return (unsigned short)(r >> 16);
}

#define GLL16(gp, lp)                                                         \
  __builtin_amdgcn_global_load_lds(                                           \
      (const __attribute__((address_space(1))) unsigned int*)(gp),            \
      (__attribute__((address_space(3))) unsigned int*)(lp), 16, 0, 0)

// ---------------- fused: X fp32 -> bf16 + per-row squared norm -------------
// Summation order identical to the verified vq_xsq -> bit-identical xsq.
__global__ __launch_bounds__(256) void vq_xcvt(const float* __restrict__ X,
                                               unsigned short* __restrict__ Xb,
                                               float* __restrict__ xsq) {
  const int wave = threadIdx.x >> 6;
  const int lane = threadIdx.x & 63;
  const int row = blockIdx.x * 4 + wave;
  const float4* r = (const float4*)(X + (size_t)row * DDIM);
  ushort4* ob = (ushort4*)(Xb + (size_t)row * DDIM);
  float s = 0.f;
#pragma unroll
  for (int t = 0; t < 2; ++t) {
    float4 v = r[lane + 64 * t];
    s += v.x * v.x + v.y * v.y + v.z * v.z + v.w * v.w;
    ushort4 o;
    o.x = bf16_rne(v.x); o.y = bf16_rne(v.y);
    o.z = bf16_rne(v.z); o.w = bf16_rne(v.w);
    ob[lane + 64 * t] = o;
  }
#pragma unroll
  for (int m = 32; m > 0; m >>= 1) s += __shfl_xor(s, m, 64);
  if (lane == 0) xsq[row] = s;
}

// ---------------- per-row squared norms (fallback path only) ----------------
__global__ __launch_bounds__(256) void vq_xsq(const float* __restrict__ X,
                                              float* __restrict__ xsq) {
  const int wave = threadIdx.x >> 6;
  const int lane = threadIdx.x & 63;
  const int row = blockIdx.x * 4 + wave;
  const float4* r = (const float4*)(X + (size_t)row * DDIM);
  float s = 0.f;
#pragma unroll
  for (int t = 0; t < 2; ++t) {
    float4 v = r[lane + 64 * t];
    s += v.x * v.x + v.y * v.y + v.z * v.z + v.w * v.w;
  }
#pragma unroll
  for (int m = 32; m > 0; m >>= 1) s += __shfl_xor(s, m, 64);
  if (lane == 0) xsq[row] = s;
}

// ---------------- fp32 -> bf16 convert (RNE), used for CB ----------------
__global__ __launch_bounds__(256) void vq_cvt(const float* __restrict__ src,
                                              unsigned short* __restrict__ dst,
                                              int n4) {
  int i = blockIdx.x * 256 + threadIdx.x;
  const int stride = gridDim.x * 256;
  for (; i < n4; i += stride) {
    float4 v = ((const float4*)src)[i];
    ushort4 o;
    o.x = bf16_rne(v.x); o.y = bf16_rne(v.y);
    o.z = bf16_rne(v.z); o.w = bf16_rne(v.w);
    ((ushort4*)dst)[i] = o;
  }
}

// ------ bf16 MFMA GEMM, 128x256 tile, 2-phase prefetch, wave-private epi ---
// 256 thr = 4 waves: wr = w>>1 (row half), wc = w&1 (col block).
// Wave output: rows wr*64+[0,64), cols wc*128+[0,128) = ONE BM block.
// LDS: As[2][8192] (128r x 64B), Bs[2][16384] (256r x 64B), dbuf by kc&1.
// Row layout: 32 bf16 = 4 quarters of 16B; physical quarter = q ^ fsw(row).
// Staging (per wave per step): A granules 2w,2w+1; B granules 4w..4w+3
// (16 rows each); lane l -> row g*16+(l>>2), quarter (l&3)^fsw(row), dst
// base+l*16 (GLL16 wave-linear dest).
// Loop: STAGE(buf^1, kc+1) issued BEFORE compute(buf); closing
// __syncthreads drains vmcnt -> prefetch latency hidden under compute.
__global__ __launch_bounds__(256, 2) void vq_gemmw(const unsigned short* __restrict__ Xb,
                                                   const unsigned short* __restrict__ CBb,
                                                   float* __restrict__ BM,
                                                   unsigned int* __restrict__ Msk) {
  __shared__ __align__(16) unsigned char As[2][8192];
  __shared__ __align__(16) unsigned char Bs[2][16384];
  __shared__ unsigned int mskW[4][64][2];

  const int tid  = threadIdx.x;
  const int lane = tid & 63;
  const int w    = tid >> 6;
  const int wr   = w >> 1, wc = w & 1;
  const int row0 = blockIdx.x * 128;
  const int col0 = blockIdx.y * 256;
  const int quad = lane >> 4, c16 = lane & 15;

  // per-lane staging sources (A: 2 granules, B: 4 granules of 16 rows)
  const int mloc = lane >> 2, qp = lane & 3;
  const int gA0 = 2 * w, gA1 = 2 * w + 1;
  const int maA0 = gA0 * 16 + mloc, maA1 = gA1 * 16 + mloc;
  const unsigned char* pA0 = (const unsigned char*)Xb +
      (size_t)(row0 + maA0) * 1024 + (size_t)((qp ^ fsw(maA0)) * 16);
  const unsigned char* pA1 = (const unsigned char*)Xb +
      (size_t)(row0 + maA1) * 1024 + (size_t)((qp ^ fsw(maA1)) * 16);
  const unsigned char* pBs[4];
#pragma unroll
  for (int g = 0; g < 4; ++g) {
    int ma = (4 * w + g) * 16 + mloc;
    pBs[g] = (const unsigned char*)CBb +
        (size_t)(col0 + ma) * 1024 + (size_t)((qp ^ fsw(ma)) * 16);
  }

  f32x4 acc[4][8];
#pragma unroll
  for (int i = 0; i < 4; ++i)
#pragma unroll
    for (int j = 0; j < 8; ++j) acc[i][j] = (f32x4)0.f;

#define STAGEW(BUF, KC_)                                                      \
  do {                                                                        \
    const size_t ko_ = (size_t)(KC_) * 64;                                    \
    GLL16(pA0 + ko_, As[BUF] + gA0 * 1024);                                   \
    GLL16(pA1 + ko_, As[BUF] + gA1 * 1024);                                   \
    GLL16(pBs[0] + ko_, Bs[BUF] + (4 * w + 0) * 1024);                        \
    GLL16(pBs[1] + ko_, Bs[BUF] + (4 * w + 1) * 1024);                        \
    GLL16(pBs[2] + ko_, Bs[BUF] + (4 * w + 2) * 1024);                        \
    GLL16(pBs[3] + ko_, Bs[BUF] + (4 * w + 3) * 1024);                        \
  } while (0)

  STAGEW(0, 0);
  __syncthreads();

#pragma unroll
  for (int kc = 0; kc < 16; ++kc) {
    const int cur = kc & 1;
    if (kc < 15) STAGEW(cur ^ 1, kc + 1);

    short8 a[4], b[8];
#pragma unroll
    for (int i = 0; i < 4; ++i) {
      int m = wr * 64 + i * 16 + c16;
      a[i] = *(const short8*)(As[cur] + m * 64 + ((quad ^ fsw(m)) * 16));
    }
#pragma unroll
    for (int j = 0; j < 8; ++j) {
      int n = wc * 128 + j * 16 + c16;
      b[j] = *(const short8*)(Bs[cur] + n * 64 + ((quad ^ fsw(n)) * 16));
    }
#pragma unroll
    for (int i = 0; i < 4; ++i)
#pragma unroll
      for (int j = 0; j < 8; ++j)
        acc[i][j] = __builtin_amdgcn_mfma_f32_16x16x32_bf16(a[i], b[j], acc[i][j], 0, 0, 0);
    __syncthreads();   // drains vmcnt (prefetch) + lgkm, then barrier
  }

  // ---- wave-private epilogue: this wave's 64 rows x its 128-col BM block.
  // C/D layout: col = c16, row-in-frag = quad*4 + reg (learn_hip m89).
  mskW[w][lane][0] = 0u;
  mskW[w][lane][1] = 0u;
  asm volatile("s_waitcnt lgkmcnt(0)" ::: "memory");

  float vloc[4][4];
#pragma unroll
  for (int i = 0; i < 4; ++i)
#pragma unroll
    for (int reg = 0; reg < 4; ++reg) {
      float v = acc[i][0][reg];
#pragma unroll
      for (int j = 1; j < 8; ++j) v = fminf(v, acc[i][j][reg]);
#pragma unroll
      for (int m = 1; m < 16; m <<= 1) v = fminf(v, __shfl_xor(v, m, 64));
      vloc[i][reg] = v;
      float thr = v + MARGIN;
#pragma unroll
      for (int j = 0; j < 8; ++j) {
        if (acc[i][j][reg] <= thr) {
          int cl = j * 16 + c16;              // col in BM block, 0..127
          int p = cl >> 1;                    // pair 0..63
          int r = i * 16 + quad * 4 + reg;    // row in wave, 0..63
          atomicOr(&mskW[w][r][p >> 5], 1u << (p & 31));
        }
      }
    }
  asm volatile("s_waitcnt lgkmcnt(0)" ::: "memory");

  if (c16 == 0) {
#pragma unroll
    for (int i = 0; i < 4; ++i)
#pragma unroll
      for (int reg = 0; reg < 4; ++reg) {
        int r = i * 16 + quad * 4 + reg;
        int grow = row0 + wr * 64 + r;
        size_t o = (size_t)grow * 64 + (size_t)blockIdx.y * 2 + wc;
        BM[o]          = vloc[i][reg];
        Msk[o * 2 + 0] = mskW[w][r][0];
        Msk[o * 2 + 1] = mskW[w][r][1];
      }
  }
}

// -------- candidate expansion + exact fp32 recheck + fused gather ---------
// X row staged in LDS by the whole wave (coalesced); serial exact chain
// reads X from LDS and CB from global with unroll 8. Bit-exact.
__global__ __launch_bounds__(256) void vq_select(const float* __restrict__ X,
                                                 const float* __restrict__ CB,
                                                 const float* __restrict__ xsq,
                                                 const float* __restrict__ BM,
                                                 const unsigned int* __restrict__ Msk,
                                                 float* __restrict__ idx_f,
                                                 float* __restrict__ out_codes,
                                                 float* __restrict__ out_zqx) {
  __shared__ float xrow[4][DDIM];          // 8 KB: per-wave staged X row
  __shared__ unsigned short cand[4][128];
  __shared__ int cnt[4];
  const int lane = threadIdx.x & 63;
  const int w    = threadIdx.x >> 6;
  const int row  = blockIdx.x * 4 + w;

  if (lane == 0) cnt[w] = 0;

  // cooperative X-row stage (coalesced: 64 lanes x 2 float4)
  const float4* xr = (const float4*)(X + (size_t)row * DDIM);
  float4* xl4 = (float4*)xrow[w];
  xl4[lane]      = xr[lane];
  xl4[lane + 64] = xr[lane + 64];
  __syncthreads();

  const size_t bo = (size_t)row * 64 + lane;
  float bmv = BM[bo];
  float g = bmv;
#pragma unroll
  for (int m = 1; m < 64; m <<= 1) g = fminf(g, __shfl_xor(g, m, 64));
  if (bmv <= g + MARGIN) {
    unsigned m0 = Msk[bo * 2 + 0], m1 = Msk[bo * 2 + 1];
    while (m0) {
      int p = __ffs(m0) - 1; m0 &= m0 - 1;
      int base = lane * 128 + p * 2;
      int o = atomicAdd(&cnt[w], 2);
      if (o + 1 < 128) { cand[w][o] = (unsigned short)base; cand[w][o + 1] = (unsigned short)(base + 1); }
    }
    while (m1) {
      int p = __ffs(m1) - 1; m1 &= m1 - 1;
      int base = lane * 128 + 64 + p * 2;
      int o = atomicAdd(&cnt[w], 2);
      if (o + 1 < 128) { cand[w][o] = (unsigned short)base; cand[w][o + 1] = (unsigned short)(base + 1); }
    }
  }
  __syncthreads();

  int n = cnt[w]; n = n > 128 ? 128 : n;
  float bd = __builtin_inff();
  int   bi = 0x7fffffff;
  const float4* xl = (const float4*)xrow[w];
  const float   xs = xsq[row];
  for (int c = lane; c < n; c += 64) {
    int code = cand[w][c];
    const float4* cr = (const float4*)(CB + (size_t)code * DDIM);
    float acc = 0.f;   // EXACT chain: k ascending, single fp32 fma accumulator
#pragma unroll 8
    for (int k = 0; k < 128; ++k) {
      float4 xv = xl[k], cv = cr[k];
      acc = fmaf(xv.x, cv.x, acc);
      acc = fmaf(xv.y, cv.y, acc);
      acc = fmaf(xv.z, cv.z, acc);
      acc = fmaf(xv.w, cv.w, acc);
    }
    float d = fmaf(2.f, acc, xs);
    if (d < bd || (d == bd && code < bi)) { bd = d; bi = code; }
  }
#pragma unroll
  for (int m = 1; m < 64; m <<= 1) {
    float od = __shfl_xor(bd, m, 64);
    int   oi = __shfl_xor(bi, m, 64);
    if (od < bd || (od == bd && oi < bi)) { bd = od; bi = oi; }
  }
  if (lane == 0) idx_f[row] = (float)bi;
  // fused gather: bi is uniform across the wave after the butterfly
  const float4* cr2 = (const float4*)(CB + (size_t)bi * DDIM);
  float4* oc = (float4*)(out_codes + (size_t)row * DDIM);
  float4* oz = (float4*)(out_zqx   + (size_t)row * DDIM);
#pragma unroll
  for (int t = 0; t < 2; ++t) {
    float4 v = cr2[lane + 64 * t];
    oc[lane + 64 * t] = v;
    oz[lane + 64 * t] = v;
  }
}

// ---------------- gather (fallback path only) ----------------
__global__ __launch_bounds__(256) void vq_gather(const float* __restrict__ CB,
                                                 const int* __restrict__ idx_i,
                                                 float* __restrict__ out_codes,
                                                 float* __restrict__ out_zqx) {
  const int t = threadIdx.x;
  const int r = blockIdx.x * 2 + (t >> 7);
  const int q = t & 127;
  const int k = idx_i[r];
  float4 v = *(const float4*)(CB + (size_t)k * DDIM + q * 4);
  *(float4*)(out_codes + (size_t)r * DDIM + q * 4) = v;
  *(float4*)(out_zqx   + (size_t)r * DDIM + q * 4) = v;
}

// ---------------- fallback: fp32 fused GEMM+argmin (known-good) ----
constexpr int FMT = 64, FNT = 128, FDC = 32;
constexpr int FAS = FMT + 2, FBS = FNT + 2;
__global__ __launch_bounds__(256, 2) void vq_argmin_fb(const float* __restrict__ X,
                                                       const float* __restrict__ CB,
                                                       const float* __restrict__ xsq,
                                                       int* __restrict__ idx_i,
                                                       float* __restrict__ idx_f) {
  __shared__ float As[FDC][FAS];
  __shared__ float Bs[FDC][FBS];
  const int tid = threadIdx.x;
  const int tx = tid & 15, ty = tid >> 4;
  const int row_base = blockIdx.x * FMT;
  float xs[4];
#pragma unroll
  for (int i = 0; i < 4; ++i) xs[i] = xsq[row_base + ty * 4 + i];
  float bestv[4]; int besti[4];
#pragma unroll
  for (int i = 0; i < 4; ++i) { bestv[i] = __builtin_inff(); besti[i] = 0; }
  for (int c0 = 0; c0 < KC; c0 += FNT) {
    float acc[4][8];
#pragma unroll
    for (int i = 0; i < 4; ++i)
#pragma unroll
      for (int j = 0; j < 8; ++j) acc[i][j] = 0.f;
    for (int d0 = 0; d0 < DDIM; d0 += FDC) {
      __syncthreads();
#pragma unroll
      for (int s = 0; s < 2; ++s) {
        int f = tid + 256 * s; int r = f >> 3, q = f & 7;
        float4 v = *(const float4*)(X + (size_t)(row_base + r) * DDIM + d0 + q * 4);
        As[q * 4 + 0][r] = v.x; As[q * 4 + 1][r] = v.y;
        As[q * 4 + 2][r] = v.z; As[q * 4 + 3][r] = v.w;
      }
#pragma unroll
      for (int s = 0; s < 4; ++s) {
        int f = tid + 256 * s; int r = f >> 3, q = f & 7;
        float4 v = *(const float4*)(CB + (size_t)(c0 + r) * DDIM + d0 + q * 4);
        Bs[q * 4 + 0][r] = v.x; Bs[q * 4 + 1][r] = v.y;
        Bs[q * 4 + 2][r] = v.z; Bs[q * 4 + 3][r] = v.w;
      }
      __syncthreads();
#pragma unroll
      for (int kk = 0; kk < FDC; ++kk) {
        float a[4], b[8];
        *(float2*)&a[0] = *(const float2*)&As[kk][ty * 4 + 0];
        *(float2*)&a[2] = *(const float2*)&As[kk][ty * 4 + 2];
        *(float2*)&b[0] = *(const float2*)&Bs[kk][tx * 4 + 0];
        *(float2*)&b[2] = *(const float2*)&Bs[kk][tx * 4 + 2];
        *(float2*)&b[4] = *(const float2*)&Bs[kk][64 + tx * 4 + 0];
        *(float2*)&b[6] = *(const float2*)&Bs[kk][64 + tx * 4 + 2];
#pragma unroll
        for (int i = 0; i < 4; ++i)
#pragma unroll
          for (int j = 0; j < 8; ++j) acc[i][j] = fmaf(a[i], b[j], acc[i][j]);
      }
    }
#pragma unroll
    for (int j = 0; j < 8; ++j) {
      int c = c0 + ((j < 4) ? (tx * 4 + j) : (64 + tx * 4 + (j - 4)));
#pragma unroll
      for (int i = 0; i < 4; ++i) {
        float d = fmaf(2.f, acc[i][j], xs[i]);
        if (d < bestv[i] || (d == bestv[i] && c < besti[i])) { bestv[i] = d; besti[i] = c; }
      }
    }
  }
#pragma unroll
  for (int m = 1; m < 16; m <<= 1) {
#pragma unroll
    for (int i = 0; i < 4; ++i) {
      float ov = __shfl_xor(bestv[i], m, 64);
      int   oi = __shfl_xor(besti[i], m, 64);
      if (ov < bestv[i] || (ov == bestv[i] && oi < besti[i])) { bestv[i] = ov; besti[i] = oi; }
    }
  }
  if (tx == 0) {
#pragma unroll
    for (int i = 0; i < 4; ++i) {
      int r = row_base + ty * 4 + i;
      idx_i[r] = besti[i];
      idx_f[r] = (float)besti[i];
    }
  }
}

extern "C" void kernel_launch(void* const* d_in, const int* in_sizes, int n_in,
                              void* d_out, int out_size, void* d_ws, size_t ws_size,
                              hipStream_t stream) {
  const float* X  = (const float*)d_in[0];
  const float* CB = (const float*)d_in[1];

  float* out       = (float*)d_out;
  float* out_codes = out;
  float* out_zqx   = out + (size_t)BN * DDIM;
  float* out_idxf  = out + 2 * (size_t)BN * DDIM;

  unsigned char* w0 = (unsigned char*)d_ws;
  const size_t NEED = (64ull << 20) + 2 * (size_t)BN * 4;

  if (ws_size >= NEED) {
    unsigned short* Xb  = (unsigned short*)w0;                    // 32 MB
    unsigned short* CBb = (unsigned short*)(w0 + (32ull << 20));  //  8 MB
    float*        BM    = (float*)(w0 + (40ull << 20));           //  8 MB
    unsigned int* Msk   = (unsigned int*)(w0 + (48ull << 20));    // 16 MB
    float*        xsq   = (float*)(w0 + (64ull << 20));

    vq_xcvt  <<<BN / 4, 256, 0, stream>>>(X, Xb, xsq);
    vq_cvt   <<<128, 256, 0, stream>>>(CB, CBb, KC * (DDIM / 4));
    vq_gemmw <<<dim3(BN / 128, KC / 256), 256, 0, stream>>>(Xb, CBb, BM, Msk);
    vq_select<<<BN / 4, 256, 0, stream>>>(X, CB, xsq, BM, Msk, out_idxf,
                                          out_codes, out_zqx);
  } else {
    float* xsq   = (float*)w0;
    int*   idx_i = (int*)(w0 + (size_t)BN * 4);
    vq_xsq      <<<BN / 4, 256, 0, stream>>>(X, xsq);
    vq_argmin_fb<<<BN / FMT, 256, 0, stream>>>(X, CB, xsq, idx_i, out_idxf);
    vq_gather   <<<BN / 2, 256, 0, stream>>>(CB, idx_i, out_codes, out_zqx);
  }
}